// Round 13
// baseline (34194.202 us; speedup 1.0000x reference)
//
#include <hip/hip_runtime.h>
#include <hip/hip_bf16.h>

// LSTM: B=128, T=1024, D=H=768.
// R13: R12 minus the register bomb. R12 cut fabric volume 4x (FETCH 1.58GB
// ->447MB) but VGPR hit the 256 cap (whh_frag[48]=192 regs) -> spills /
// issue-starvation doubled the time. Single change: W_hh is STREAMED from
// L2 per step (cached, read-only-safe, L2-resident 576KB/XCD) exactly like
// W_ih already was. Partition, LDS h-sharing (4.6MB/step device-scope
// traffic), sync protocol, layouts: identical to R12.

typedef __attribute__((ext_vector_type(8))) short short8v;   // 8 bf16 = 4 VGPR
typedef __attribute__((ext_vector_type(16))) float f32x16;   // 32x32 acc

constexpr int B_ = 128, T_ = 1024, D_ = 768, H_ = 768;
constexpr int NWG = 96;                                // 24 jq x 4 batch-blocks

constexpr size_t FINAL_U32 = 1025ull * 16;             // final[t][16] u32
constexpr size_t PING_OFF  = 66048;                    // 512-aligned
constexpr size_t HSLOT_SH  = 96ull * 128 * 8;          // 98304 shorts = 196608 B
constexpr size_t BIAS_OFF  = PING_OFF + 393216;        // 459264  (bias_img 3072 f32)
constexpr size_t WHH_OFF   = BIAS_OFF + 12288;         // 471552  (img 4718592 B)
constexpr size_t WIH_OFF   = WHH_OFF + 4718592;        // 5190144
constexpr size_t XT_OFF    = WIH_OFF + 4718592;        // 9908736
constexpr size_t WS_NEED   = XT_OFF + 201326592;       // 211235328 (< known-good 213270528)

__device__ __forceinline__ unsigned short f2bf(float f) {
  union { float f; unsigned u; } v; v.f = f;
  unsigned r = v.u + 0x7FFF + ((v.u >> 16) & 1);       // RNE
  return (unsigned short)(r >> 16);
}
__device__ __forceinline__ float sigmf(float x) { return 1.0f / (1.0f + __expf(-x)); }
__device__ __forceinline__ float tanhf_(float x) {
  float ax = fabsf(x);
  float e = __expf(-2.0f * ax);
  float t = (1.0f - e) / (1.0f + e);
  return copysignf(t, x);
}

// ---------------- P1: x -> xTb[t][kb][b][ko] bf16, LDS-tiled transpose ----
__global__ void k_xT(const float* __restrict__ x, unsigned short* __restrict__ xTb) {
  __shared__ float tile[16][776];
  const int t = blockIdx.x;
  const int tid = threadIdx.x;
  for (int chunk = 0; chunk < 8; ++chunk) {
    #pragma unroll
    for (int i = 0; i < 12; ++i) {
      int id = i * 256 + tid;
      int bl = id / 192, d4 = id % 192;
      int b = chunk * 16 + bl;
      float4 v = *(const float4*)(x + ((size_t)b * T_ + t) * D_ + d4 * 4);
      *(float4*)&tile[bl][d4 * 4] = v;
    }
    __syncthreads();
    #pragma unroll
    for (int i = 0; i < 6; ++i) {
      int id = i * 256 + tid;
      int kb = id >> 4, bl = id & 15;
      int b = chunk * 16 + bl;
      const float* src = &tile[bl][kb * 8];
      unsigned short tmp[8];
      #pragma unroll
      for (int k = 0; k < 8; ++k) tmp[k] = f2bf(src[k]);
      *(short8v*)(xTb + (((size_t)t * 96 + kb) * 128 + b) * 8) = *(short8v*)tmp;
    }
    __syncthreads();
  }
}

// ---------------- P2: weight images, lane-contiguous --------------------
// img[jqw(96)][kc(96)][col(32)][8] bf16 : value = W[grow(col,jqw)][kc*8..+8]
// grow = (col>>3)*768 + jq*32 + w*8 + (col&7)  (4 gates x 8 h-cols per 32 rows)
__global__ void k_prep_w(const float* __restrict__ whh, const float* __restrict__ wih,
                         unsigned short* __restrict__ Whh_img,
                         unsigned short* __restrict__ Wih_img) {
  int id  = blockIdx.x * 256 + threadIdx.x;            // exactly 589824
  int img = id / 294912;
  int rem = id - img * 294912;
  int jqw = rem / 3072;
  int rem2 = rem - jqw * 3072;
  int kc  = rem2 >> 5;
  int col = rem2 & 31;
  int grow = (col >> 3) * H_ + (jqw >> 2) * 32 + (jqw & 3) * 8 + (col & 7);
  const float* W = img ? wih : whh;
  const float* p = W + (size_t)grow * D_ + kc * 8;
  float4 v0 = *(const float4*)p;
  float4 v1 = *(const float4*)(p + 4);
  unsigned short o[8] = {f2bf(v0.x), f2bf(v0.y), f2bf(v0.z), f2bf(v0.w),
                         f2bf(v1.x), f2bf(v1.y), f2bf(v1.z), f2bf(v1.w)};
  unsigned short* dst = (img ? Wih_img : Whh_img) + (size_t)rem * 8;
  *(short8v*)dst = *(short8v*)o;
}

// ---------------- P3: bias_img, h0 -> ping slot0, zero final -------------
__global__ void k_prep_s(const float* __restrict__ h0,
                         const float* __restrict__ bih, const float* __restrict__ bhh,
                         unsigned short* __restrict__ hping,
                         float* __restrict__ bias_img,
                         unsigned* __restrict__ finalc) {
  int id = blockIdx.x * 256 + threadIdx.x;             // exactly 98304
  int b = id / 768, j = id - b * 768;
  hping[(size_t)(j >> 3) * 1024 + b * 8 + (j & 7)] = f2bf(h0[id]);
  if (id < 3072) {
    int jqw = id >> 5, col = id & 31;
    int grow = (col >> 3) * H_ + (jqw >> 2) * 32 + (jqw & 3) * 8 + (col & 7);
    bias_img[id] = bih[grow] + bhh[grow];
  }
  if (id < (int)FINAL_U32) finalc[id] = 0;
}

// ---------------- main recurrent kernel ----------------------------------
__launch_bounds__(256, 1)
__global__ void k_lstm(const unsigned short* __restrict__ xTb,
                       const unsigned short* __restrict__ Whh_img,
                       const unsigned short* __restrict__ Wih_img,
                       const float* __restrict__ bias_img,
                       const float* __restrict__ c0,
                       unsigned short* __restrict__ hping, // [2][96][128][8] bf16
                       unsigned* finalc,                   // [1025][16]
                       float* __restrict__ out,
                       float* __restrict__ hT,
                       float* __restrict__ cT) {
  __shared__ __align__(16) unsigned short hbuf[96 * 32 * 8];   // 48 KB h block

  const int wj   = blockIdx.x;        // = jq*4 + c
  const int jq   = wj >> 2;
  const int c    = wj & 3;            // batch block: rows 32c..32c+31
  const int tid  = threadIdx.x;
  const int wave = tid >> 6;          // gaterow group: rows jq*128+32w..+32
  const int lane = tid & 63;
  const int col  = lane & 31;         // batch-in-block / W-row-in-group
  const int kh   = lane >> 5;
  const int jqw  = jq * 4 + wave;

  const int bg = 32 * c + col;        // global batch row
  const int jg = jq * 32 + wave * 8 + 4 * kh;   // global h-col base (4 per lane)

  // W streamed from L2 every step (cached, read-only): no big register arrays
  const unsigned short* whh_base = Whh_img + (size_t)jqw * 96 * 32 * 8;
  const unsigned short* wih_base = Wih_img + (size_t)jqw * 96 * 32 * 8;

  float bias_r[16];
  #pragma unroll
  for (int q = 0; q < 16; ++q)
    bias_r[q] = bias_img[jqw * 32 + (q & 3) + 8 * (q >> 2) + 4 * kh];

  float c_r[4];
  {
    float4 v = *(const float4*)(c0 + (size_t)bg * H_ + jg);
    c_r[0] = v.x; c_r[1] = v.y; c_r[2] = v.z; c_r[3] = v.w;
  }

  f32x16 accs[4];
  { // phase X for t=0: A=W_ih (L2), B=x (L2)
    #pragma unroll
    for (int q = 0; q < 16; ++q) {
      accs[0][q] = bias_r[q]; accs[1][q] = 0.f; accs[2][q] = 0.f; accs[3][q] = 0.f;
    }
    #pragma unroll
    for (int f = 0; f < 48; ++f) {
      int kc = 2 * f + kh;
      short8v w = *(const short8v*)(wih_base + (kc * 32 + col) * 8);
      short8v xv = *(const short8v*)(xTb + (((size_t)0 * 96 + kc) * 128 + bg) * 8);
      accs[f & 3] = __builtin_amdgcn_mfma_f32_32x32x16_bf16(w, xv, accs[f & 3], 0, 0, 0);
    }
  }

  for (int t = 0; t < T_; ++t) {
    if (t > 0) {
      if (wave == 0) {
        const unsigned* fp = finalc + (size_t)t * 16;
        for (;;) {
          unsigned v = __hip_atomic_load(fp, __ATOMIC_RELAXED, __HIP_MEMORY_SCOPE_AGENT);
          if (v >= (unsigned)NWG) break;
          __builtin_amdgcn_s_sleep(4);
        }
      }
      __syncthreads();
      asm volatile("" ::: "memory");
    }

    // stage h[768][32-batch-block] (48KB) -> LDS, device-scope loads
    {
      const unsigned short* hb_rd = hping + (size_t)(t & 1) * HSLOT_SH;
      short8v tmp[12];
      #pragma unroll
      for (int i = 0; i < 12; ++i) {
        int id = i * 256 + tid;            // id = kb*32 + bpos
        int kb = id >> 5, bpos = id & 31;
        const unsigned short* p = hb_rd + ((size_t)kb * 128 + 32 * c + bpos) * 8;
        asm volatile("global_load_dwordx4 %0, %1, off sc0 sc1"
                     : "=v"(tmp[i]) : "v"(p));
      }
      asm volatile("s_waitcnt vmcnt(0)" ::: "memory");
      #pragma unroll
      for (int i = 0; i < 12; ++i) {
        int id = i * 256 + tid;
        *(short8v*)&hbuf[(size_t)id * 8] = tmp[i];
      }
      __syncthreads();
    }

    // phase H: A=W_hh (L2-cached stream), B=h (LDS)
    #pragma unroll
    for (int f = 0; f < 48; ++f) {
      int kc = 2 * f + kh;
      short8v w = *(const short8v*)(whh_base + (kc * 32 + col) * 8);
      short8v hB = *(const short8v*)&hbuf[(kc * 32 + col) * 8];
      accs[f & 3] = __builtin_amdgcn_mfma_f32_32x32x16_bf16(w, hB, accs[f & 3], 0, 0, 0);
    }

    f32x16 g;
    #pragma unroll
    for (int q = 0; q < 16; ++q)
      g[q] = (accs[0][q] + accs[1][q]) + (accs[2][q] + accs[3][q]);

    float hnew[4];
    #pragma unroll
    for (int m = 0; m < 4; ++m) {
      float gi = g[m];
      float gf = g[4 + m];
      float gg = g[8 + m];
      float go = g[12 + m];
      float cn = sigmf(gf) * c_r[m] + sigmf(gi) * tanhf_(gg);
      c_r[m] = cn;
      hnew[m] = sigmf(go) * tanhf_(cn);
    }

    // h exchange: 8B sc1 write-through (kb = jqw)
    union { ushort4 s; unsigned long long u; } hv;
    hv.s = (ushort4){f2bf(hnew[0]), f2bf(hnew[1]), f2bf(hnew[2]), f2bf(hnew[3])};
    __hip_atomic_store(
        (unsigned long long*)(hping + (size_t)((t + 1) & 1) * HSLOT_SH +
                              ((size_t)jqw * 128 + bg) * 8 + 4 * kh),
        hv.u, __ATOMIC_RELAXED, __HIP_MEMORY_SCOPE_AGENT);

    // release: per-wave ack, barrier (all waves + LDS WAR), ONE arrival add
    asm volatile("s_waitcnt vmcnt(0)" ::: "memory");
    __syncthreads();
    if (tid == 0)
      __hip_atomic_fetch_add(finalc + (size_t)(t + 1) * 16, 1u,
                             __ATOMIC_RELAXED, __HIP_MEMORY_SCOPE_AGENT);

    // out stores AFTER the release (off the critical path)
    float4 ov = make_float4(hnew[0], hnew[1], hnew[2], hnew[3]);
    *(float4*)(out + ((size_t)bg * T_ + t) * H_ + jg) = ov;
    if (t == T_ - 1) {
      *(float4*)(hT + (size_t)bg * H_ + jg) = ov;
      float4 cv = make_float4(c_r[0], c_r[1], c_r[2], c_r[3]);
      *(float4*)(cT + (size_t)bg * H_ + jg) = cv;
    }

    // phase X for t+1 (L2 cached reads), in the shadow of the wait
    if (t + 1 < T_) {
      #pragma unroll
      for (int q = 0; q < 16; ++q) {
        accs[0][q] = bias_r[q]; accs[1][q] = 0.f; accs[2][q] = 0.f; accs[3][q] = 0.f;
      }
      const unsigned short* xp = xTb + (size_t)(t + 1) * 96 * 128 * 8;
      #pragma unroll
      for (int f = 0; f < 48; ++f) {
        int kc = 2 * f + kh;
        short8v w = *(const short8v*)(wih_base + (kc * 32 + col) * 8);
        short8v xv = *(const short8v*)(xp + ((size_t)kc * 128 + bg) * 8);
        accs[f & 3] = __builtin_amdgcn_mfma_f32_32x32x16_bf16(w, xv, accs[f & 3], 0, 0, 0);
      }
    }
  }
}

extern "C" void kernel_launch(void* const* d_in, const int* in_sizes, int n_in,
                              void* d_out, int out_size, void* d_ws, size_t ws_size,
                              hipStream_t stream) {
  const float* x   = (const float*)d_in[0];
  const float* h0  = (const float*)d_in[1];
  const float* c0  = (const float*)d_in[2];
  const float* wih = (const float*)d_in[3];
  const float* whh = (const float*)d_in[4];
  const float* bih = (const float*)d_in[5];
  const float* bhh = (const float*)d_in[6];

  float* out = (float*)d_out;
  float* hT  = out + (size_t)B_ * T_ * H_;
  float* cT  = hT + (size_t)B_ * H_;

  if (ws_size < WS_NEED) return;  // visible failure instead of OOB corruption

  char* ws = (char*)d_ws;
  unsigned*       finalc = (unsigned*)(ws);
  unsigned short* hping  = (unsigned short*)(ws + PING_OFF);
  float*          biasc  = (float*)(ws + BIAS_OFF);
  unsigned short* WhhI   = (unsigned short*)(ws + WHH_OFF);
  unsigned short* WihI   = (unsigned short*)(ws + WIH_OFF);
  unsigned short* xTp    = (unsigned short*)(ws + XT_OFF);

  k_xT<<<dim3(T_), dim3(256), 0, stream>>>(x, xTp);
  k_prep_w<<<dim3(589824 / 256), dim3(256), 0, stream>>>(whh, wih, WhhI, WihI);
  k_prep_s<<<dim3((B_ * H_) / 256), dim3(256), 0, stream>>>(h0, bih, bhh, hping, biasc, finalc);
  k_lstm<<<dim3(NWG), dim3(256), 0, stream>>>(xTp, WhhI, WihI, biasc, c0, hping, finalc, out, hT, cT);
}

// Round 15
// 24130.365 us; speedup vs baseline: 1.4171x; 1.4171x over previous
//
#include <hip/hip_runtime.h>
#include <hip/hip_bf16.h>

// LSTM: B=128, T=1024, D=H=768.
// R15 = R14 with the compile fix (__builtin_nontemporal_store needs a native
// clang vector, not HIP float4). Design unchanged:
// (a) Whh pinned in LDS (R13 streamed it -> 17.3GB HBM refetch thrash);
// (b) 192 WGs x 128 thr (64 gaterows x 32 batch): 2x CUs + half per-WG h
//     bytes -> h drain (per-CU ~8.2B/cy ceiling, R9 arithmetic) ~2.4us;
// (c) out stores NON-TEMPORAL to stop L3 eviction of W/x;
// (d) h staged once to LDS (48KB) shared by both waves, device-scope loads
//     (consumer-cached h is outlawed: R7/R10/R11 failures);
// Sync: proven single final[t] counter, threshold 192.

typedef __attribute__((ext_vector_type(8))) short short8v;   // 8 bf16 = 4 VGPR
typedef __attribute__((ext_vector_type(16))) float f32x16;   // 32x32 acc
typedef __attribute__((ext_vector_type(4))) float f32x4;     // native vec for nt-store

constexpr int B_ = 128, T_ = 1024, D_ = 768, H_ = 768;
constexpr int NWG = 192;                               // 48 jq x 4 batch-blocks

constexpr size_t FINAL_U32 = 1025ull * 16;             // final[t][16] u32
constexpr size_t PING_OFF  = 66048;                    // 512-aligned
constexpr size_t HSLOT_SH  = 96ull * 128 * 8;          // 98304 shorts = 196608 B
constexpr size_t BIAS_OFF  = PING_OFF + 393216;        // 459264  (bias_img 3072 f32)
constexpr size_t WHH_OFF   = BIAS_OFF + 12288;         // 471552  (img 4718592 B)
constexpr size_t WIH_OFF   = WHH_OFF + 4718592;        // 5190144
constexpr size_t XT_OFF    = WIH_OFF + 4718592;        // 9908736
constexpr size_t WS_NEED   = XT_OFF + 201326592;       // 211235328 (< known-good 213270528)

__device__ __forceinline__ unsigned short f2bf(float f) {
  union { float f; unsigned u; } v; v.f = f;
  unsigned r = v.u + 0x7FFF + ((v.u >> 16) & 1);       // RNE
  return (unsigned short)(r >> 16);
}
__device__ __forceinline__ float sigmf(float x) { return 1.0f / (1.0f + __expf(-x)); }
__device__ __forceinline__ float tanhf_(float x) {
  float ax = fabsf(x);
  float e = __expf(-2.0f * ax);
  float t = (1.0f - e) / (1.0f + e);
  return copysignf(t, x);
}

// ---------------- P1: x -> xTb[t][kb][b][ko] bf16, LDS-tiled transpose ----
__global__ void k_xT(const float* __restrict__ x, unsigned short* __restrict__ xTb) {
  __shared__ float tile[16][776];
  const int t = blockIdx.x;
  const int tid = threadIdx.x;
  for (int chunk = 0; chunk < 8; ++chunk) {
    #pragma unroll
    for (int i = 0; i < 12; ++i) {
      int id = i * 256 + tid;
      int bl = id / 192, d4 = id % 192;
      int b = chunk * 16 + bl;
      float4 v = *(const float4*)(x + ((size_t)b * T_ + t) * D_ + d4 * 4);
      *(float4*)&tile[bl][d4 * 4] = v;
    }
    __syncthreads();
    #pragma unroll
    for (int i = 0; i < 6; ++i) {
      int id = i * 256 + tid;
      int kb = id >> 4, bl = id & 15;
      int b = chunk * 16 + bl;
      const float* src = &tile[bl][kb * 8];
      unsigned short tmp[8];
      #pragma unroll
      for (int k = 0; k < 8; ++k) tmp[k] = f2bf(src[k]);
      *(short8v*)(xTb + (((size_t)t * 96 + kb) * 128 + b) * 8) = *(short8v*)tmp;
    }
    __syncthreads();
  }
}

// ---------------- P2: weight images, lane-contiguous --------------------
// img[s(96)][kc(96)][col(32)][8] bf16 : value = W[grow][kc*8..+8]
// grow = (col>>3)*768 + s*8 + (col&7)   (4 gates x 8 h-cols per 32-row tile)
__global__ void k_prep_w(const float* __restrict__ whh, const float* __restrict__ wih,
                         unsigned short* __restrict__ Whh_img,
                         unsigned short* __restrict__ Wih_img) {
  int id  = blockIdx.x * 256 + threadIdx.x;            // exactly 589824
  int img = id / 294912;
  int rem = id - img * 294912;
  int s   = rem / 3072;
  int rem2 = rem - s * 3072;
  int kc  = rem2 >> 5;
  int col = rem2 & 31;
  int grow = (col >> 3) * H_ + s * 8 + (col & 7);
  const float* W = img ? wih : whh;
  const float* p = W + (size_t)grow * D_ + kc * 8;
  float4 v0 = *(const float4*)p;
  float4 v1 = *(const float4*)(p + 4);
  unsigned short o[8] = {f2bf(v0.x), f2bf(v0.y), f2bf(v0.z), f2bf(v0.w),
                         f2bf(v1.x), f2bf(v1.y), f2bf(v1.z), f2bf(v1.w)};
  unsigned short* dst = (img ? Wih_img : Whh_img) + (size_t)rem * 8;
  *(short8v*)dst = *(short8v*)o;
}

// ---------------- P3: bias_img, h0 -> ping slot0, zero final -------------
__global__ void k_prep_s(const float* __restrict__ h0,
                         const float* __restrict__ bih, const float* __restrict__ bhh,
                         unsigned short* __restrict__ hping,
                         float* __restrict__ bias_img,
                         unsigned* __restrict__ finalc) {
  int id = blockIdx.x * 256 + threadIdx.x;             // exactly 98304
  int b = id / 768, j = id - b * 768;
  hping[(size_t)(j >> 3) * 1024 + b * 8 + (j & 7)] = f2bf(h0[id]);
  if (id < 3072) {
    int s = id >> 5, col = id & 31;
    int grow = (col >> 3) * H_ + s * 8 + (col & 7);
    bias_img[id] = bih[grow] + bhh[grow];
  }
  if (id < (int)FINAL_U32) finalc[id] = 0;
}

// ---------------- main recurrent kernel ----------------------------------
__launch_bounds__(128, 1)
__global__ void k_lstm(const unsigned short* __restrict__ xTb,
                       const unsigned short* __restrict__ Whh_img,
                       const unsigned short* __restrict__ Wih_img,
                       const float* __restrict__ bias_img,
                       const float* __restrict__ c0,
                       unsigned short* __restrict__ hping, // [2][96][128][8] bf16
                       unsigned* finalc,                   // [1025][16]
                       float* __restrict__ out,
                       float* __restrict__ hT,
                       float* __restrict__ cT) {
  __shared__ __align__(16) unsigned short Whh_l[2 * 96 * 32 * 8];  // 96 KB, pinned
  __shared__ __align__(16) unsigned short hbuf[96 * 32 * 8];       // 48 KB h block

  const int wj   = blockIdx.x;        // = jq*4 + c
  const int jq   = wj >> 2;           // 16 h-cols per jq
  const int c    = wj & 3;            // batch block: rows 32c..32c+31
  const int tid  = threadIdx.x;
  const int w    = tid >> 6;          // wave: 32-row tile (s = jq*2+w)
  const int lane = tid & 63;
  const int col  = lane & 31;         // batch-in-block / W-row-in-tile
  const int kh   = lane >> 5;
  const int s    = jq * 2 + w;        // slice id [0,96)

  const int bg = 32 * c + col;        // global batch row
  const int jg = s * 8 + 4 * kh;      // global h-col base (4 per lane)

  { // stage Whh slices jq*2, jq*2+1 into LDS once (cached one-time reads)
    const short8v* src = (const short8v*)(Whh_img + (size_t)(jq * 2) * 24576);
    short8v* dst = (short8v*)Whh_l;
    for (int i = tid; i < 6144; i += 128) dst[i] = src[i];
  }
  __syncthreads();

  const unsigned short* wih_base = Wih_img + (size_t)s * 24576;

  float bias_r[16];
  #pragma unroll
  for (int q = 0; q < 16; ++q)
    bias_r[q] = bias_img[s * 32 + (q & 3) + 8 * (q >> 2) + 4 * kh];

  float c_r[4];
  {
    float4 v = *(const float4*)(c0 + (size_t)bg * H_ + jg);
    c_r[0] = v.x; c_r[1] = v.y; c_r[2] = v.z; c_r[3] = v.w;
  }

  f32x16 accs[4];
  { // phase X for t=0: A=W_ih (cached), B=x (cached)
    #pragma unroll
    for (int q = 0; q < 16; ++q) {
      accs[0][q] = bias_r[q]; accs[1][q] = 0.f; accs[2][q] = 0.f; accs[3][q] = 0.f;
    }
    #pragma unroll
    for (int f = 0; f < 48; ++f) {
      int kc = 2 * f + kh;
      short8v wv = *(const short8v*)(wih_base + (kc * 32 + col) * 8);
      short8v xv = *(const short8v*)(xTb + ((size_t)kc * 128 + bg) * 8);
      accs[f & 3] = __builtin_amdgcn_mfma_f32_32x32x16_bf16(wv, xv, accs[f & 3], 0, 0, 0);
    }
  }

  for (int t = 0; t < T_; ++t) {
    if (t > 0) {
      if (w == 0) {
        const unsigned* fp = finalc + (size_t)t * 16;
        for (;;) {
          unsigned v = __hip_atomic_load(fp, __ATOMIC_RELAXED, __HIP_MEMORY_SCOPE_AGENT);
          if (v >= (unsigned)NWG) break;
          __builtin_amdgcn_s_sleep(4);
        }
      }
      __syncthreads();
      asm volatile("" ::: "memory");
    }

    // stage h[768][32-batch-block] (48KB) -> LDS, device-scope loads
    {
      const unsigned short* hb_rd = hping + (size_t)(t & 1) * HSLOT_SH;
      short8v tmp[24];
      #pragma unroll
      for (int i = 0; i < 24; ++i) {
        int id = i * 128 + tid;            // id = kb*32 + bpos
        int kb = id >> 5, bpos = id & 31;
        const unsigned short* p = hb_rd + ((size_t)kb * 128 + 32 * c + bpos) * 8;
        asm volatile("global_load_dwordx4 %0, %1, off sc0 sc1"
                     : "=v"(tmp[i]) : "v"(p));
      }
      asm volatile("s_waitcnt vmcnt(0)" ::: "memory");
      #pragma unroll
      for (int i = 0; i < 24; ++i) {
        int id = i * 128 + tid;
        *(short8v*)&hbuf[(size_t)id * 8] = tmp[i];
      }
      __syncthreads();
    }

    // phase H: A=W_hh (LDS, pinned), B=h (LDS)
    #pragma unroll
    for (int f = 0; f < 48; ++f) {
      int kc = 2 * f + kh;
      short8v wv = *(const short8v*)&Whh_l[((w * 96 + kc) * 32 + col) * 8];
      short8v hB = *(const short8v*)&hbuf[(kc * 32 + col) * 8];
      accs[f & 3] = __builtin_amdgcn_mfma_f32_32x32x16_bf16(wv, hB, accs[f & 3], 0, 0, 0);
    }

    f32x16 g;
    #pragma unroll
    for (int q = 0; q < 16; ++q)
      g[q] = (accs[0][q] + accs[1][q]) + (accs[2][q] + accs[3][q]);

    float hnew[4];
    #pragma unroll
    for (int m = 0; m < 4; ++m) {
      float gi = g[m];
      float gf = g[4 + m];
      float gg = g[8 + m];
      float go = g[12 + m];
      float cn = sigmf(gf) * c_r[m] + sigmf(gi) * tanhf_(gg);
      c_r[m] = cn;
      hnew[m] = sigmf(go) * tanhf_(cn);
    }

    // h exchange: 8B sc1 write-through (kb = s)
    union { ushort4 sv; unsigned long long u; } hv;
    hv.sv = (ushort4){f2bf(hnew[0]), f2bf(hnew[1]), f2bf(hnew[2]), f2bf(hnew[3])};
    __hip_atomic_store(
        (unsigned long long*)(hping + (size_t)((t + 1) & 1) * HSLOT_SH +
                              ((size_t)s * 128 + bg) * 8 + 4 * kh),
        hv.u, __ATOMIC_RELAXED, __HIP_MEMORY_SCOPE_AGENT);

    // release: per-wave ack, barrier (all waves + hbuf WAR), ONE arrival add
    asm volatile("s_waitcnt vmcnt(0)" ::: "memory");
    __syncthreads();
    if (tid == 0)
      __hip_atomic_fetch_add(finalc + (size_t)(t + 1) * 16, 1u,
                             __ATOMIC_RELAXED, __HIP_MEMORY_SCOPE_AGENT);

    // out stores AFTER the release — NON-TEMPORAL (protect L3 W/x residency)
    f32x4 ov = {hnew[0], hnew[1], hnew[2], hnew[3]};
    __builtin_nontemporal_store(ov, (f32x4*)(out + ((size_t)bg * T_ + t) * H_ + jg));
    if (t == T_ - 1) {
      *(f32x4*)(hT + (size_t)bg * H_ + jg) = ov;
      f32x4 cv = {c_r[0], c_r[1], c_r[2], c_r[3]};
      *(f32x4*)(cT + (size_t)bg * H_ + jg) = cv;
    }

    // phase X for t+1 (cached reads, in the shadow of the wait)
    if (t + 1 < T_) {
      #pragma unroll
      for (int q = 0; q < 16; ++q) {
        accs[0][q] = bias_r[q]; accs[1][q] = 0.f; accs[2][q] = 0.f; accs[3][q] = 0.f;
      }
      const unsigned short* xp = xTb + (size_t)(t + 1) * 96 * 128 * 8;
      #pragma unroll
      for (int f = 0; f < 48; ++f) {
        int kc = 2 * f + kh;
        short8v wv = *(const short8v*)(wih_base + (kc * 32 + col) * 8);
        short8v xv = *(const short8v*)(xp + ((size_t)kc * 128 + bg) * 8);
        accs[f & 3] = __builtin_amdgcn_mfma_f32_32x32x16_bf16(wv, xv, accs[f & 3], 0, 0, 0);
      }
    }
  }
}

extern "C" void kernel_launch(void* const* d_in, const int* in_sizes, int n_in,
                              void* d_out, int out_size, void* d_ws, size_t ws_size,
                              hipStream_t stream) {
  const float* x   = (const float*)d_in[0];
  const float* h0  = (const float*)d_in[1];
  const float* c0  = (const float*)d_in[2];
  const float* wih = (const float*)d_in[3];
  const float* whh = (const float*)d_in[4];
  const float* bih = (const float*)d_in[5];
  const float* bhh = (const float*)d_in[6];

  float* out = (float*)d_out;
  float* hT  = out + (size_t)B_ * T_ * H_;
  float* cT  = hT + (size_t)B_ * H_;

  if (ws_size < WS_NEED) return;  // visible failure instead of OOB corruption

  char* ws = (char*)d_ws;
  unsigned*       finalc = (unsigned*)(ws);
  unsigned short* hping  = (unsigned short*)(ws + PING_OFF);
  float*          biasc  = (float*)(ws + BIAS_OFF);
  unsigned short* WhhI   = (unsigned short*)(ws + WHH_OFF);
  unsigned short* WihI   = (unsigned short*)(ws + WIH_OFF);
  unsigned short* xTp    = (unsigned short*)(ws + XT_OFF);

  k_xT<<<dim3(T_), dim3(256), 0, stream>>>(x, xTp);
  k_prep_w<<<dim3(589824 / 256), dim3(256), 0, stream>>>(whh, wih, WhhI, WihI);
  k_prep_s<<<dim3((B_ * H_) / 256), dim3(256), 0, stream>>>(h0, bih, bhh, hping, biasc, finalc);
  k_lstm<<<dim3(NWG), dim3(128), 0, stream>>>(xTp, WhhI, WihI, biasc, c0, hping, finalc, out, hT, cT);
}